// Round 10
// baseline (829.936 us; speedup 1.0000x reference)
//
#include <hip/hip_runtime.h>
#include <cmath>

typedef __bf16 bf16;
typedef __bf16 bf16x8 __attribute__((ext_vector_type(8)));
typedef __bf16 bf16x4 __attribute__((ext_vector_type(4)));
typedef __bf16 bf16x2 __attribute__((ext_vector_type(2)));
typedef float f32x4 __attribute__((ext_vector_type(4)));
typedef float f32x16 __attribute__((ext_vector_type(16)));
typedef int i32x4 __attribute__((ext_vector_type(4)));
typedef int i32x2 __attribute__((ext_vector_type(2)));

#define S_LEN 2048
#define QK_LD 3072       // NHEADS * 192

__device__ __forceinline__ void async_copy16(const bf16* g, bf16* l) {
    __builtin_amdgcn_global_load_lds(
        (const __attribute__((address_space(1))) void*)g,
        (__attribute__((address_space(3))) void*)l, 16, 0, 0);
}

__device__ __forceinline__ unsigned packbf(float a, float b) {
    bf16x2 v; v[0] = (bf16)a; v[1] = (bf16)b;
    return __builtin_bit_cast(unsigned, v);
}

// ---------------- cast x (fp32) -> bf16 ----------------
__global__ __launch_bounds__(256) void cast_f32_bf16(const float* __restrict__ in,
                                                     bf16* __restrict__ out) {
    size_t i = ((size_t)blockIdx.x * 256 + threadIdx.x) * 8;
    float4 a = *(const float4*)(in + i);
    float4 b = *(const float4*)(in + i + 4);
    bf16x8 v;
    v[0] = (bf16)a.x; v[1] = (bf16)a.y; v[2] = (bf16)a.z; v[3] = (bf16)a.w;
    v[4] = (bf16)b.x; v[5] = (bf16)b.y; v[6] = (bf16)b.z; v[7] = (bf16)b.w;
    *(bf16x8*)(out + i) = v;
}

// ---------------- fused transpose-cast of all 7 weights, one dispatch ----------------
struct TSeg { const float* src; bf16* dst; int K, N, blk0; };
struct TArgs { TSeg s[7]; };

__global__ __launch_bounds__(256) void transpose_all(TArgs a) {
    __shared__ float tile[64][68];
    int b = blockIdx.x, si = 0;
#pragma unroll
    for (int i = 1; i < 7; ++i) if (b >= a.s[i].blk0) si = i;
    TSeg sg = a.s[si];
    int local = b - sg.blk0;
    int kTiles = sg.K >> 6;
    int kt = local % kTiles, nt = local / kTiles;
    int k0 = kt * 64, n0 = nt * 64;
    int K = sg.K, N = sg.N;
    int t = threadIdx.x;
#pragma unroll
    for (int i = 0; i < 4; ++i) {
        int c = t + i * 256;
        int r = c >> 4, off = (c & 15) * 4;
        float4 v = *(const float4*)(sg.src + (size_t)(k0 + r) * N + n0 + off);
        tile[r][off] = v.x; tile[r][off + 1] = v.y;
        tile[r][off + 2] = v.z; tile[r][off + 3] = v.w;
    }
    __syncthreads();
#pragma unroll
    for (int i = 0; i < 2; ++i) {
        int c = t + i * 256;
        int nr = c >> 3, koff = (c & 7) * 8;
        bf16x8 v;
#pragma unroll
        for (int j = 0; j < 8; ++j) v[j] = (bf16)tile[koff + j][nr];
        *(bf16x8*)(sg.dst + (size_t)(n0 + nr) * K + k0 + koff) = v;
    }
}

// ---------------- bias concat + rope table, one dispatch ----------------
__global__ __launch_bounds__(256) void setup_small(const float* __restrict__ bd,
                                                   const float* __restrict__ bqd,
                                                   const float* __restrict__ bkr,
                                                   const float* __restrict__ bqu,
                                                   const float* __restrict__ bqr,
                                                   float* __restrict__ bcat,
                                                   float2* __restrict__ tab) {
    if (blockIdx.x < 21) {
        int i = blockIdx.x * 256 + threadIdx.x;
        if (i < 512) bcat[i] = bd[i];
        else if (i < 1280) bcat[i] = bqd[i - 512];
        else if (i < 2304) bcat[i] = bkr[i - 1280];
        else if (i < 4352) bcat[i] = bqu[i - 2304];
        else if (i < 5376) bcat[i] = bqr[i - 4352];
    } else {
        int id = (blockIdx.x - 21) * 256 + threadIdx.x;   // 65536
        int s = id >> 5, i = id & 31;
        float f = expf(-0.2878231366242557f * (float)i);  // ln(10000)/32
        float ang = (float)s * f;
        tab[id] = make_float2(cosf(ang), sinf(ang));
    }
}

// ---------------- m97-style bf16 GEMM core with fused epilogues ----------------
// mode 1: fp32 out0, stride Ndim
// mode 4: col<1280 -> bf16 out0 (xproj, 2304); col>=1280 -> rope -> out1 (kbuf)
// mode 5: col<2048 -> head-scatter out0 (qbuf); col>=2048 -> rope -> out0
// mode 6: head-scatter out0 (kbuf) + transposed pack out1 (vt[bh][d][s])
__device__ __forceinline__ void gemm_core(const bf16* __restrict__ A, int lda,
                                          const bf16* __restrict__ Bt,
                                          const float* __restrict__ bias,
                                          void* __restrict__ out0,
                                          void* __restrict__ out1,
                                          int Ndim, int Kdim, int mode,
                                          const float2* __restrict__ tab,
                                          int bn, int bm, bf16* As, bf16* Bs) {
    int t = threadIdx.x;
    int w = t >> 6, lane = t & 63;
    int wm = (w >> 1) * 64, wn = (w & 1) * 64;
    int l15 = lane & 15, q4 = lane >> 4;
    f32x4 acc[4][4] = {};

    int lrow = lane >> 2;
    int lcol = (lane & 3) * 8;
    int c0 = w * 2, c1 = w * 2 + 1;
    const bf16* aS0 = A  + (size_t)(bm * 128 + c0 * 16 + lrow) * lda + lcol;
    const bf16* aS1 = A  + (size_t)(bm * 128 + c1 * 16 + lrow) * lda + lcol;
    const bf16* bS0 = Bt + (size_t)(bn * 128 + c0 * 16 + lrow) * Kdim + lcol;
    const bf16* bS1 = Bt + (size_t)(bn * 128 + c1 * 16 + lrow) * Kdim + lcol;
    bf16* aD0 = &As[c0 * 512]; bf16* aD1 = &As[c1 * 512];
    bf16* bD0 = &Bs[c0 * 512]; bf16* bD1 = &Bs[c1 * 512];

    for (int kt = 0; kt < Kdim; kt += 32) {
        async_copy16(aS0 + kt, aD0);
        async_copy16(aS1 + kt, aD1);
        async_copy16(bS0 + kt, bD0);
        async_copy16(bS1 + kt, bD1);
        __syncthreads();
        bf16x8 af[4], bfr[4];
#pragma unroll
        for (int mb = 0; mb < 4; ++mb)
            af[mb] = *(const bf16x8*)&As[(wm + mb * 16 + l15) * 32 + q4 * 8];
#pragma unroll
        for (int nb = 0; nb < 4; ++nb)
            bfr[nb] = *(const bf16x8*)&Bs[(wn + nb * 16 + l15) * 32 + q4 * 8];
#pragma unroll
        for (int mb = 0; mb < 4; ++mb)
#pragma unroll
            for (int nb = 0; nb < 4; ++nb)
                acc[mb][nb] = __builtin_amdgcn_mfma_f32_16x16x32_bf16(
                    af[mb], bfr[nb], acc[mb][nb], 0, 0, 0);
        __syncthreads();
    }

#pragma unroll
    for (int mb = 0; mb < 4; ++mb) {
        int row = bm * 128 + wm + mb * 16 + q4 * 4;
#pragma unroll
        for (int nb = 0; nb < 4; ++nb) {
            int col = bn * 128 + wn + nb * 16 + l15;
            float bv = bias[col];
            if (mode == 1) {
#pragma unroll
                for (int r = 0; r < 4; ++r)
                    ((float*)out0)[(size_t)(row + r) * Ndim + col] = acc[mb][nb][r] + bv;
            } else if (mode == 4) {
                if (col < 1280) {
#pragma unroll
                    for (int r = 0; r < 4; ++r)
                        ((bf16*)out0)[(size_t)(row + r) * 2304 + col] =
                            (bf16)(acc[mb][nb][r] + bv);
                } else {
                    int rel = col - 1280;
                    int hh = rel >> 6, idx = rel & 63, ii = idx >> 1, odd = idx & 1;
#pragma unroll
                    for (int r = 0; r < 4; ++r) {
                        float vv = acc[mb][nb][r] + bv;
                        float pp = __shfl_xor(vv, 1, 64);
                        float2 cs = tab[((row + r) & 2047) * 32 + ii];
                        float o = vv * cs.x + (odd ? pp * cs.y : -pp * cs.y);
                        ((bf16*)out1)[(size_t)(row + r) * QK_LD + hh * 192 + 128 + idx] =
                            (bf16)o;
                    }
                }
            } else if (mode == 5) {
                if (col < 2048) {
                    int hh = col >> 7, dd = col & 127;
#pragma unroll
                    for (int r = 0; r < 4; ++r)
                        ((bf16*)out0)[(size_t)(row + r) * QK_LD + hh * 192 + dd] =
                            (bf16)(acc[mb][nb][r] + bv);
                } else {
                    int rel = col - 2048;
                    int hh = rel >> 6, idx = rel & 63, ii = idx >> 1, odd = idx & 1;
#pragma unroll
                    for (int r = 0; r < 4; ++r) {
                        float vv = acc[mb][nb][r] + bv;
                        float pp = __shfl_xor(vv, 1, 64);
                        float2 cs = tab[((row + r) & 2047) * 32 + ii];
                        float o = vv * cs.x + (odd ? pp * cs.y : -pp * cs.y);
                        ((bf16*)out0)[(size_t)(row + r) * QK_LD + hh * 192 + 128 + idx] =
                            (bf16)o;
                    }
                }
            } else {   // mode 6: kv_up -> kbuf scatter + vt transpose-pack
                int hh = col >> 7, dd = col & 127;
                bf16x4 pack;
#pragma unroll
                for (int r = 0; r < 4; ++r) {
                    float vv = acc[mb][nb][r] + bv;
                    ((bf16*)out0)[(size_t)(row + r) * QK_LD + hh * 192 + dd] = (bf16)vv;
                    pack[r] = (bf16)vv;
                }
                int bidx = row >> 11, srow = row & 2047;
                *(bf16x4*)((bf16*)out1 +
                           ((size_t)(bidx * 16 + hh) * 128 + dd) * S_LEN + srow) = pack;
            }
        }
    }
}

// bijective XCD chunk swizzle (unchanged from v11; neutral but harmless)
__device__ __forceinline__ void xcd_chunk(int gx, int& bn, int& bm) {
    int lin = blockIdx.y * gx + blockIdx.x;
    int nwg = gx * gridDim.y;
    int chunk = nwg >> 3;
    int nl = (lin & 7) * chunk + (lin >> 3);
    bn = nl % gx;
    bm = nl / gx;
}

__global__ __launch_bounds__(256) void gemm_bt(const bf16* __restrict__ A, int lda,
                                               const bf16* __restrict__ Bt,
                                               const float* __restrict__ bias,
                                               void* __restrict__ out0,
                                               void* __restrict__ out1,
                                               int Ndim, int Kdim, int mode,
                                               const float2* __restrict__ tab) {
    __shared__ bf16 As[128 * 32];
    __shared__ bf16 Bs[128 * 32];
    int bn, bm;
    xcd_chunk(gridDim.x, bn, bm);
    gemm_core(A, lda, Bt, bias, out0, out1, Ndim, Kdim, mode, tab,
              bn, bm, As, Bs);
}

// fused up-projection GEMMs: bn<16 -> kv_up (mode 6, K=512); bn>=16 -> q_up (mode 5, K=768)
__global__ __launch_bounds__(256) void gemm_up(const bf16* __restrict__ xproj,
                                               const bf16* __restrict__ WuT,
                                               const float* __restrict__ bu,
                                               void* __restrict__ kbuf,
                                               void* __restrict__ vt,
                                               const bf16* __restrict__ W2T,
                                               const float* __restrict__ bq,
                                               void* __restrict__ qbuf,
                                               const float2* __restrict__ tab) {
    __shared__ bf16 As[128 * 32];
    __shared__ bf16 Bs[128 * 32];
    int bn, bm;
    xcd_chunk(gridDim.x, bn, bm);
    if (bn < 16)
        gemm_core(xproj, 2304, WuT, bu, kbuf, vt, 2048, 512, 6, tab,
                  bn, bm, As, Bs);
    else
        gemm_core(xproj + 512, 2304, W2T, bq, qbuf, nullptr, 3072, 768, 5, tab,
                  bn - 16, bm, As, Bs);
}

// ---------------- attention v12: split-K (C=2) for 4 blocks/CU ----------------
// Softmax uses a fixed clamp (no running max), so K-chunks combine exactly:
// each chunk writes unnormalized O (f32) + per-row denom; attn_reduce merges.
// Grid 32 x 32 (y: qt = y&15, ck = y>>4) = 1024 blocks = 4 blocks/CU =
// 16 waves/CU (LDS 4x40KB = 160KB exactly). Attacks the 8-waves/CU latency
// wall (v8/v11 both ~114us at MfmaUtil 33%).
__global__ __launch_bounds__(256, 4) void attn(const bf16* __restrict__ qbuf,
                                               const bf16* __restrict__ kbuf,
                                               const bf16* __restrict__ vt,
                                               float* __restrict__ pacc,
                                               float* __restrict__ dn) {
    __shared__ bf16 Ks[2][32 * 192];    // 32 keys x 192d; 8B-unit swz: u8 ^ (row&15)
    __shared__ bf16 Vs[2][128 * 32];    // 128 d x 32 k; line-pair swz
    int bh = blockIdx.x;                // 0..31  (lin%8 = bh%8 -> XCD affinity)
    int qt = blockIdx.y & 15;           // 0..15
    int ck = blockIdx.y >> 4;           // 0..1  K-chunk (keys [ck*1024, ck*1024+1024))
    int b = bh >> 4, h = bh & 15;
    int t = threadIdx.x, w = t >> 6, lane = t & 63;
    int l31 = lane & 31, hl = lane >> 5;
    const float scale2 = 0.1275174333f; // (1/sqrt(128)) * log2(e)

    // Q as B-operand frags (32x32x16): lane holds Q[row=l31][d = c*16 + hl*8 + j]
    bf16x8 qf[12];
    {
        size_t rbase = (size_t)(b * S_LEN + qt * 128 + w * 32 + l31) * QK_LD
                       + h * 192 + hl * 8;
#pragma unroll
        for (int c = 0; c < 12; ++c)
            qf[c] = *(const bf16x8*)(qbuf + rbase + c * 16);
    }

    f32x16 oacc[4] = {};                // [dg]  32q x 128d per wave
    float denom = 0.f;
    const bf16* kb_base = kbuf + (size_t)b * S_LEN * QK_LD + h * 192
                          + (size_t)ck * 1024 * QK_LD;
    const bf16* vt_base = vt + (size_t)bh * 128 * S_LEN + ck * 1024;

    // ---- staging index setup (256 threads: 3 K-units + 2 V-units each) ----
    int kg_[3], klA_[3], klB_[3], vg_[2], vlA_[2], vlB_[2];
#pragma unroll
    for (int i = 0; i < 3; ++i) {
        int c = t + (i << 8);           // 0..767
        int kr = c / 24, u = c % 24;
        kg_[i] = kr * QK_LD + u * 8;
        int m = kr & 15;
        klA_[i] = kr * 192 + (((2 * u) ^ m) << 2);
        klB_[i] = kr * 192 + (((2 * u + 1) ^ m) << 2);
    }
#pragma unroll
    for (int i = 0; i < 2; ++i) {
        int c = t + (i << 8);           // 0..511
        int vd = c >> 2, u = c & 3;
        vg_[i] = vd * S_LEN + u * 8;
        int line = vd >> 1, lm = line & 15;
        int sl = 8 * (vd & 1) + 2 * u;
        vlA_[i] = line * 64 + ((sl ^ lm) << 2);
        vlB_[i] = line * 64 + (((sl + 1) ^ lm) << 2);
    }

    // read-side per-lane constants
    int mK = l31 & 15;
    int kRow = l31 * 192;
    int vLM = l31 >> 1;
    int vSlotB = 8 * (l31 & 1) + 2 * hl;

    // ---- prologue: stage tile 0 of this chunk ----
    i32x4 kreg[3], vreg[2];
#pragma unroll
    for (int i = 0; i < 3; ++i) kreg[i] = *(const i32x4*)(kb_base + kg_[i]);
#pragma unroll
    for (int i = 0; i < 2; ++i) vreg[i] = *(const i32x4*)(vt_base + vg_[i]);
#pragma unroll
    for (int i = 0; i < 3; ++i) {
        i32x2 lo; lo[0] = kreg[i][0]; lo[1] = kreg[i][1];
        i32x2 hi; hi[0] = kreg[i][2]; hi[1] = kreg[i][3];
        *(i32x2*)&Ks[0][klA_[i]] = lo;
        *(i32x2*)&Ks[0][klB_[i]] = hi;
    }
#pragma unroll
    for (int i = 0; i < 2; ++i) {
        i32x2 lo; lo[0] = vreg[i][0]; lo[1] = vreg[i][1];
        i32x2 hi; hi[0] = vreg[i][2]; hi[1] = vreg[i][3];
        *(i32x2*)&Vs[0][vlA_[i]] = lo;
        *(i32x2*)&Vs[0][vlB_[i]] = hi;
    }
    __syncthreads();

    int cur = 0;
    for (int kt = 0; kt < 32; ++kt) {
        // prefetch tile kt+1 (lands under compute)
        if (kt < 31) {
            const bf16* kb = kb_base + (size_t)(kt + 1) * 32 * QK_LD;
#pragma unroll
            for (int i = 0; i < 3; ++i) kreg[i] = *(const i32x4*)(kb + kg_[i]);
#pragma unroll
            for (int i = 0; i < 2; ++i)
                vreg[i] = *(const i32x4*)(vt_base + (kt + 1) * 32 + vg_[i]);
        }

        // QK^T: S^T = K(32k x 16d) . Q^T(16d x 32q) per chunk; 12 chunks
        f32x16 sacc = {};
        __builtin_amdgcn_s_setprio(1);
#pragma unroll
        for (int c = 0; c < 12; ++c) {
            int u0 = 4 * c + 2 * hl;
            i32x2 lo = *(const i32x2*)&Ks[cur][kRow + ((u0 ^ mK) << 2)];
            i32x2 hi = *(const i32x2*)&Ks[cur][kRow + (((u0 + 1) ^ mK) << 2)];
            i32x4 kv; kv[0] = lo[0]; kv[1] = lo[1]; kv[2] = hi[0]; kv[3] = hi[1];
            bf16x8 kb = __builtin_bit_cast(bf16x8, kv);
            sacc = __builtin_amdgcn_mfma_f32_32x32x16_bf16(kb, qf[c], sacc, 0, 0, 0);
        }
        __builtin_amdgcn_s_setprio(0);

        // softmax + in-register P redistribution (32x32 layout).
        // lane holds S[k=(r&3)+8*(r>>2)+4*hl][q=l31]; PV A-frag needs
        // P[q=l31][k = s*16 + hl*8 + j]. Exchange lane l <-> l^32.
        unsigned W[8], pw[8];
#pragma unroll
        for (int m = 0; m < 8; ++m) {
            float e0 = __builtin_amdgcn_exp2f(fminf(sacc[2 * m] * scale2, 72.0f));
            float e1 = __builtin_amdgcn_exp2f(fminf(sacc[2 * m + 1] * scale2, 72.0f));
            denom += e0 + e1;
            W[m] = packbf(e0, e1);
        }
#pragma unroll
        for (int m = 0; m < 8; ++m)
            pw[m] = (unsigned)__shfl_xor((int)W[m], 32, 64);
        bf16x8 paf[2];
#pragma unroll
        for (int s = 0; s < 2; ++s) {
            unsigned A = hl ? pw[4 * s + 2] : W[4 * s + 0];
            unsigned B = hl ? pw[4 * s + 3] : W[4 * s + 1];
            unsigned C = hl ? W[4 * s + 2] : pw[4 * s + 0];
            unsigned D = hl ? W[4 * s + 3] : pw[4 * s + 1];
            i32x4 di; di[0] = (int)A; di[1] = (int)B; di[2] = (int)C; di[3] = (int)D;
            paf[s] = __builtin_bit_cast(bf16x8, di);
        }

        // PV: P(32q x 16k) . V(16k x 32d); 4 d-groups x 2 k-steps
        __builtin_amdgcn_s_setprio(1);
#pragma unroll
        for (int dg = 0; dg < 4; ++dg) {
#pragma unroll
            for (int s = 0; s < 2; ++s) {
                int line = dg * 16 + (l31 >> 1);
                int s0 = (vSlotB + 4 * s) ^ vLM;
                int s1 = (vSlotB + 4 * s + 1) ^ vLM;
                i32x2 lo = *(const i32x2*)&Vs[cur][line * 64 + (s0 << 2)];
                i32x2 hi = *(const i32x2*)&Vs[cur][line * 64 + (s1 << 2)];
                i32x4 vv; vv[0] = lo[0]; vv[1] = lo[1]; vv[2] = hi[0]; vv[3] = hi[1];
                bf16x8 vb = __builtin_bit_cast(bf16x8, vv);
                oacc[dg] = __builtin_amdgcn_mfma_f32_32x32x16_bf16(
                    paf[s], vb, oacc[dg], 0, 0, 0);
            }
        }
        __builtin_amdgcn_s_setprio(0);

        // write tile kt+1 into the other buffer; single barrier per tile
        if (kt < 31) {
#pragma unroll
            for (int i = 0; i < 3; ++i) {
                i32x2 lo; lo[0] = kreg[i][0]; lo[1] = kreg[i][1];
                i32x2 hi; hi[0] = kreg[i][2]; hi[1] = kreg[i][3];
                *(i32x2*)&Ks[cur ^ 1][klA_[i]] = lo;
                *(i32x2*)&Ks[cur ^ 1][klB_[i]] = hi;
            }
#pragma unroll
            for (int i = 0; i < 2; ++i) {
                i32x2 lo; lo[0] = vreg[i][0]; lo[1] = vreg[i][1];
                i32x2 hi; hi[0] = vreg[i][2]; hi[1] = vreg[i][3];
                *(i32x2*)&Vs[cur ^ 1][vlA_[i]] = lo;
                *(i32x2*)&Vs[cur ^ 1][vlB_[i]] = hi;
            }
        }
        __syncthreads();
        cur ^= 1;
    }

    // denom: lanes l31 and l31+32 hold disjoint k-halves for q=l31
    denom += __shfl_xor(denom, 32, 64);

    int blk = (bh * 16 + qt) * 2 + ck;
    float* pt = pacc + (size_t)blk * 16384;
    if (hl == 0) dn[blk * 128 + w * 32 + l31] = denom;
#pragma unroll
    for (int r = 0; r < 16; ++r) {
        int rowl = (r & 3) + 8 * (r >> 2) + 4 * hl;      // q within the wave's 32
#pragma unroll
        for (int dg = 0; dg < 4; ++dg)
            pt[(w * 32 + rowl) * 128 + dg * 32 + l31] = oacc[dg][r];
    }
}

// ---------------- attn_reduce: (O0 + O1) / (d0 + d1) -> bf16 aout ----------------
__global__ __launch_bounds__(256) void attn_reduce(const float* __restrict__ pacc,
                                                   const float* __restrict__ dn,
                                                   bf16* __restrict__ aout) {
    int tile = blockIdx.x;              // 0..511 = bh*16 + qt
    int bh = tile >> 4, qt = tile & 15;
    int b = bh >> 4, h = bh & 15;
    const float* p0 = pacc + (size_t)tile * 2 * 16384;
    const float* p1 = p0 + 16384;
    const float* d0 = dn + tile * 2 * 128;
    const float* d1 = d0 + 128;
    int t = threadIdx.x;
    int col = (t & 31) * 4, rbase = t >> 5;    // 8 rows per pass, 16 passes
#pragma unroll
    for (int it = 0; it < 16; ++it) {
        int r = it * 8 + rbase;
        float inv = 1.0f / (d0[r] + d1[r]);
        f32x4 a = *(const f32x4*)(p0 + r * 128 + col);
        f32x4 c = *(const f32x4*)(p1 + r * 128 + col);
        bf16x4 o;
#pragma unroll
        for (int j = 0; j < 4; ++j) o[j] = (bf16)((a[j] + c[j]) * inv);
        *(bf16x4*)(aout + (size_t)(b * S_LEN + qt * 128 + r) * 2048 + h * 128 + col) = o;
    }
}

extern "C" void kernel_launch(void* const* d_in, const int* in_sizes, int n_in,
                              void* d_out, int out_size, void* d_ws, size_t ws_size,
                              hipStream_t stream) {
    const float* x   = (const float*)d_in[0];
    const float* Wd  = (const float*)d_in[1];
    const float* bd  = (const float*)d_in[2];
    const float* Wu  = (const float*)d_in[3];
    const float* bu  = (const float*)d_in[4];
    const float* Wqd = (const float*)d_in[5];
    const float* bqd = (const float*)d_in[6];
    const float* Wqu = (const float*)d_in[7];
    const float* bqu = (const float*)d_in[8];
    const float* Wqr = (const float*)d_in[9];
    const float* bqr = (const float*)d_in[10];
    const float* Wkr = (const float*)d_in[11];
    const float* bkr = (const float*)d_in[12];
    const float* Wo  = (const float*)d_in[13];
    const float* bo  = (const float*)d_in[14];
    float* out = (float*)d_out;

    char* p = (char*)d_ws;
    auto alloc = [&](size_t n) { char* r = p; p += (n + 255) & ~(size_t)255; return r; };
    // live-through-end buffers first
    bf16* WoT   = (bf16*)alloc((size_t)2048 * 2048 * 2);
    bf16* qbuf  = (bf16*)alloc((size_t)4096 * 3072 * 2);
    bf16* kbuf  = (bf16*)alloc((size_t)4096 * 3072 * 2);
    bf16* vt    = (bf16*)alloc((size_t)32 * 128 * 2048 * 2);
    bf16* aout  = (bf16*)alloc((size_t)4096 * 2048 * 2);
    float* bcat = (float*)alloc((size_t)5376 * 4);
    float2* tab = (float2*)alloc((size_t)65536 * 8);
    float* dn   = (float*)alloc((size_t)131072 * 4);
    // buffers dead before attn; pacc (written by attn) overlays them
    char* mark = p;
    bf16* xb    = (bf16*)alloc((size_t)4096 * 2048 * 2);
    bf16* W1T   = (bf16*)alloc((size_t)2304 * 2048 * 2);   // [Wd|Wqd|Wkr]^T
    bf16* W2T   = (bf16*)alloc((size_t)3072 * 768 * 2);    // [Wqu|Wqr]^T
    bf16* WuT   = (bf16*)alloc((size_t)2048 * 512 * 2);
    bf16* xproj = (bf16*)alloc((size_t)4096 * 2304 * 2);   // [kvc|qcmp]
    float* pacc = (float*)mark;                            // 1024 x 16384 f32 = 67.1 MB
    p = mark + (size_t)1024 * 16384 * 4;                   // extend past dead pool

    cast_f32_bf16<<<dim3(4096), dim3(256), 0, stream>>>(x, xb);

    TArgs ta;
    ta.s[0] = {Wd,  W1T,                       2048, 512,  0};
    ta.s[1] = {Wqd, W1T + (size_t)512 * 2048,  2048, 768,  256};
    ta.s[2] = {Wkr, W1T + (size_t)1280 * 2048, 2048, 1024, 640};
    ta.s[3] = {Wqu, W2T,                       768,  2048, 1152};
    ta.s[4] = {Wqr, W2T + (size_t)2048 * 768,  768,  1024, 1536};
    ta.s[5] = {Wu,  WuT,                       512,  2048, 1728};
    ta.s[6] = {Wo,  WoT,                       2048, 2048, 1984};
    transpose_all<<<dim3(3008), dim3(256), 0, stream>>>(ta);
    setup_small<<<dim3(277), dim3(256), 0, stream>>>(bd, bqd, bkr, bqu, bqr, bcat, tab);

    // GEMM1: x @ [Wd|Wqd|Wkr] -> xproj cols 0..1279, rope(k_r) -> kbuf
    gemm_bt<<<dim3(18, 32), dim3(256), 0, stream>>>(xb, 2048, W1T, bcat,
                                                    xproj, kbuf, 2304, 2048, 4, tab);
    // fused: kvc @ Wu -> kbuf + vt; qcmp @ [Wqu|Wqr] -> qbuf (+rope)
    gemm_up<<<dim3(40, 32), dim3(256), 0, stream>>>(xproj, WuT, bu, kbuf, vt,
                                                    W2T, bcat + 2304, qbuf, tab);

    attn<<<dim3(32, 32), dim3(256), 0, stream>>>(qbuf, kbuf, vt, pacc, dn);
    attn_reduce<<<dim3(512), dim3(256), 0, stream>>>(pacc, dn, aout);

    gemm_bt<<<dim3(16, 32), dim3(256), 0, stream>>>(aout, 2048, WoT, bo,
                                                    out, nullptr, 2048, 2048, 1, tab);
}

// Round 11
// 429.427 us; speedup vs baseline: 1.9327x; 1.9327x over previous
//
#include <hip/hip_runtime.h>
#include <cmath>

typedef __bf16 bf16;
typedef __bf16 bf16x8 __attribute__((ext_vector_type(8)));
typedef __bf16 bf16x4 __attribute__((ext_vector_type(4)));
typedef __bf16 bf16x2 __attribute__((ext_vector_type(2)));
typedef float f32x4 __attribute__((ext_vector_type(4)));
typedef float f32x16 __attribute__((ext_vector_type(16)));
typedef int i32x4 __attribute__((ext_vector_type(4)));
typedef int i32x2 __attribute__((ext_vector_type(2)));

#define S_LEN 2048
#define QK_LD 3072       // NHEADS * 192

__device__ __forceinline__ void async_copy16(const bf16* g, bf16* l) {
    __builtin_amdgcn_global_load_lds(
        (const __attribute__((address_space(1))) void*)g,
        (__attribute__((address_space(3))) void*)l, 16, 0, 0);
}

__device__ __forceinline__ unsigned packbf(float a, float b) {
    bf16x2 v; v[0] = (bf16)a; v[1] = (bf16)b;
    return __builtin_bit_cast(unsigned, v);
}

// ---------------- cast x (fp32) -> bf16 ----------------
__global__ __launch_bounds__(256) void cast_f32_bf16(const float* __restrict__ in,
                                                     bf16* __restrict__ out) {
    size_t i = ((size_t)blockIdx.x * 256 + threadIdx.x) * 8;
    float4 a = *(const float4*)(in + i);
    float4 b = *(const float4*)(in + i + 4);
    bf16x8 v;
    v[0] = (bf16)a.x; v[1] = (bf16)a.y; v[2] = (bf16)a.z; v[3] = (bf16)a.w;
    v[4] = (bf16)b.x; v[5] = (bf16)b.y; v[6] = (bf16)b.z; v[7] = (bf16)b.w;
    *(bf16x8*)(out + i) = v;
}

// ---------------- fused transpose-cast of all 7 weights, one dispatch ----------------
struct TSeg { const float* src; bf16* dst; int K, N, blk0; };
struct TArgs { TSeg s[7]; };

__global__ __launch_bounds__(256) void transpose_all(TArgs a) {
    __shared__ float tile[64][68];
    int b = blockIdx.x, si = 0;
#pragma unroll
    for (int i = 1; i < 7; ++i) if (b >= a.s[i].blk0) si = i;
    TSeg sg = a.s[si];
    int local = b - sg.blk0;
    int kTiles = sg.K >> 6;
    int kt = local % kTiles, nt = local / kTiles;
    int k0 = kt * 64, n0 = nt * 64;
    int K = sg.K, N = sg.N;
    int t = threadIdx.x;
#pragma unroll
    for (int i = 0; i < 4; ++i) {
        int c = t + i * 256;
        int r = c >> 4, off = (c & 15) * 4;
        float4 v = *(const float4*)(sg.src + (size_t)(k0 + r) * N + n0 + off);
        tile[r][off] = v.x; tile[r][off + 1] = v.y;
        tile[r][off + 2] = v.z; tile[r][off + 3] = v.w;
    }
    __syncthreads();
#pragma unroll
    for (int i = 0; i < 2; ++i) {
        int c = t + i * 256;
        int nr = c >> 3, koff = (c & 7) * 8;
        bf16x8 v;
#pragma unroll
        for (int j = 0; j < 8; ++j) v[j] = (bf16)tile[koff + j][nr];
        *(bf16x8*)(sg.dst + (size_t)(n0 + nr) * K + k0 + koff) = v;
    }
}

// ---------------- bias concat + rope table, one dispatch ----------------
__global__ __launch_bounds__(256) void setup_small(const float* __restrict__ bd,
                                                   const float* __restrict__ bqd,
                                                   const float* __restrict__ bkr,
                                                   const float* __restrict__ bqu,
                                                   const float* __restrict__ bqr,
                                                   float* __restrict__ bcat,
                                                   float2* __restrict__ tab) {
    if (blockIdx.x < 21) {
        int i = blockIdx.x * 256 + threadIdx.x;
        if (i < 512) bcat[i] = bd[i];
        else if (i < 1280) bcat[i] = bqd[i - 512];
        else if (i < 2304) bcat[i] = bkr[i - 1280];
        else if (i < 4352) bcat[i] = bqu[i - 2304];
        else if (i < 5376) bcat[i] = bqr[i - 4352];
    } else {
        int id = (blockIdx.x - 21) * 256 + threadIdx.x;   // 65536
        int s = id >> 5, i = id & 31;
        float f = expf(-0.2878231366242557f * (float)i);  // ln(10000)/32
        float ang = (float)s * f;
        tab[id] = make_float2(cosf(ang), sinf(ang));
    }
}

// ---------------- m97-style bf16 GEMM core with fused epilogues ----------------
// mode 1: fp32 out0, stride Ndim
// mode 4: col<1280 -> bf16 out0 (xproj, stride 2304); col>=1280 -> rope -> out1 (kbuf)
// mode 5: col<2048 -> head-scatter out0 (qbuf); col>=2048 -> rope -> out0 (qbuf)
// mode 6: head-scatter out0 (kbuf) + transposed pack out1 (vt[bh][d][s])
__device__ __forceinline__ void gemm_core(const bf16* __restrict__ A, int lda,
                                          const bf16* __restrict__ Bt,
                                          const float* __restrict__ bias,
                                          void* __restrict__ out0,
                                          void* __restrict__ out1,
                                          int Ndim, int Kdim, int mode,
                                          const float2* __restrict__ tab,
                                          int bn, int bm, bf16* As, bf16* Bs) {
    int t = threadIdx.x;
    int w = t >> 6, lane = t & 63;
    int wm = (w >> 1) * 64, wn = (w & 1) * 64;
    int l15 = lane & 15, q4 = lane >> 4;
    f32x4 acc[4][4] = {};

    int lrow = lane >> 2;
    int lcol = (lane & 3) * 8;
    int c0 = w * 2, c1 = w * 2 + 1;
    const bf16* aS0 = A  + (size_t)(bm * 128 + c0 * 16 + lrow) * lda + lcol;
    const bf16* aS1 = A  + (size_t)(bm * 128 + c1 * 16 + lrow) * lda + lcol;
    const bf16* bS0 = Bt + (size_t)(bn * 128 + c0 * 16 + lrow) * Kdim + lcol;
    const bf16* bS1 = Bt + (size_t)(bn * 128 + c1 * 16 + lrow) * Kdim + lcol;
    bf16* aD0 = &As[c0 * 512]; bf16* aD1 = &As[c1 * 512];
    bf16* bD0 = &Bs[c0 * 512]; bf16* bD1 = &Bs[c1 * 512];

    for (int kt = 0; kt < Kdim; kt += 32) {
        async_copy16(aS0 + kt, aD0);
        async_copy16(aS1 + kt, aD1);
        async_copy16(bS0 + kt, bD0);
        async_copy16(bS1 + kt, bD1);
        __syncthreads();
        bf16x8 af[4], bfr[4];
#pragma unroll
        for (int mb = 0; mb < 4; ++mb)
            af[mb] = *(const bf16x8*)&As[(wm + mb * 16 + l15) * 32 + q4 * 8];
#pragma unroll
        for (int nb = 0; nb < 4; ++nb)
            bfr[nb] = *(const bf16x8*)&Bs[(wn + nb * 16 + l15) * 32 + q4 * 8];
#pragma unroll
        for (int mb = 0; mb < 4; ++mb)
#pragma unroll
            for (int nb = 0; nb < 4; ++nb)
                acc[mb][nb] = __builtin_amdgcn_mfma_f32_16x16x32_bf16(
                    af[mb], bfr[nb], acc[mb][nb], 0, 0, 0);
        __syncthreads();
    }

#pragma unroll
    for (int mb = 0; mb < 4; ++mb) {
        int row = bm * 128 + wm + mb * 16 + q4 * 4;
#pragma unroll
        for (int nb = 0; nb < 4; ++nb) {
            int col = bn * 128 + wn + nb * 16 + l15;
            float bv = bias[col];
            if (mode == 1) {
#pragma unroll
                for (int r = 0; r < 4; ++r)
                    ((float*)out0)[(size_t)(row + r) * Ndim + col] = acc[mb][nb][r] + bv;
            } else if (mode == 4) {
                if (col < 1280) {
#pragma unroll
                    for (int r = 0; r < 4; ++r)
                        ((bf16*)out0)[(size_t)(row + r) * 2304 + col] =
                            (bf16)(acc[mb][nb][r] + bv);
                } else {
                    int rel = col - 1280;
                    int hh = rel >> 6, idx = rel & 63, ii = idx >> 1, odd = idx & 1;
#pragma unroll
                    for (int r = 0; r < 4; ++r) {
                        float vv = acc[mb][nb][r] + bv;
                        float pp = __shfl_xor(vv, 1, 64);
                        float2 cs = tab[((row + r) & 2047) * 32 + ii];
                        float o = vv * cs.x + (odd ? pp * cs.y : -pp * cs.y);
                        ((bf16*)out1)[(size_t)(row + r) * QK_LD + hh * 192 + 128 + idx] =
                            (bf16)o;
                    }
                }
            } else if (mode == 5) {
                if (col < 2048) {
                    int hh = col >> 7, dd = col & 127;
#pragma unroll
                    for (int r = 0; r < 4; ++r)
                        ((bf16*)out0)[(size_t)(row + r) * QK_LD + hh * 192 + dd] =
                            (bf16)(acc[mb][nb][r] + bv);
                } else {
                    int rel = col - 2048;
                    int hh = rel >> 6, idx = rel & 63, ii = idx >> 1, odd = idx & 1;
#pragma unroll
                    for (int r = 0; r < 4; ++r) {
                        float vv = acc[mb][nb][r] + bv;
                        float pp = __shfl_xor(vv, 1, 64);
                        float2 cs = tab[((row + r) & 2047) * 32 + ii];
                        float o = vv * cs.x + (odd ? pp * cs.y : -pp * cs.y);
                        ((bf16*)out0)[(size_t)(row + r) * QK_LD + hh * 192 + 128 + idx] =
                            (bf16)o;
                    }
                }
            } else {   // mode 6: kv_up -> kbuf scatter + vt transpose-pack
                int hh = col >> 7, dd = col & 127;
                bf16x4 pack;
#pragma unroll
                for (int r = 0; r < 4; ++r) {
                    float vv = acc[mb][nb][r] + bv;
                    ((bf16*)out0)[(size_t)(row + r) * QK_LD + hh * 192 + dd] = (bf16)vv;
                    pack[r] = (bf16)vv;
                }
                int bidx = row >> 11, srow = row & 2047;
                *(bf16x4*)((bf16*)out1 +
                           ((size_t)(bidx * 16 + hh) * 128 + dd) * S_LEN + srow) = pack;
            }
        }
    }
}

__global__ __launch_bounds__(256) void gemm_bt(const bf16* __restrict__ A, int lda,
                                               const bf16* __restrict__ Bt,
                                               const float* __restrict__ bias,
                                               void* __restrict__ out0,
                                               void* __restrict__ out1,
                                               int Ndim, int Kdim, int mode,
                                               const float2* __restrict__ tab) {
    __shared__ bf16 As[128 * 32];
    __shared__ bf16 Bs[128 * 32];
    gemm_core(A, lda, Bt, bias, out0, out1, Ndim, Kdim, mode, tab,
              blockIdx.x, blockIdx.y, As, Bs);
}

// fused up-projection GEMMs: bn<16 -> kv_up (mode 6, K=512); bn>=16 -> q_up (mode 5, K=768)
__global__ __launch_bounds__(256) void gemm_up(const bf16* __restrict__ xproj,
                                               const bf16* __restrict__ WuT,
                                               const float* __restrict__ bu,
                                               void* __restrict__ kbuf,
                                               void* __restrict__ vt,
                                               const bf16* __restrict__ W2T,
                                               const float* __restrict__ bq,
                                               void* __restrict__ qbuf,
                                               const float2* __restrict__ tab) {
    __shared__ bf16 As[128 * 32];
    __shared__ bf16 Bs[128 * 32];
    int bn = blockIdx.x;
    if (bn < 16)
        gemm_core(xproj, 2304, WuT, bu, kbuf, vt, 2048, 512, 6, tab,
                  bn, blockIdx.y, As, Bs);
    else
        gemm_core(xproj + 512, 2304, W2T, bq, qbuf, nullptr, 3072, 768, 5, tab,
                  bn - 16, blockIdx.y, As, Bs);
}

// ---------------- attention v8-final: 32x32x16 MFMA, 32q/wave, 8 waves, 2/SIMD ----------------
// Best measured configuration (Round 5: 111.4us attn, 430.2us total), plus
// exp2-with-folded-log2e softmax (validated in v11/v12: passed, same absmax).
__global__ __launch_bounds__(512, 2) void attn(const bf16* __restrict__ qbuf,
                                               const bf16* __restrict__ kbuf,
                                               const bf16* __restrict__ vt,
                                               bf16* __restrict__ attnout) {
    __shared__ bf16 Ks[2][32 * 192];    // 32 keys x 192d; 8B-unit swz: u8 ^ (row&15)
    __shared__ bf16 Vs[2][128 * 32];    // 128 d x 32 k; line-pair swz
    int bh = blockIdx.x;                // 0..31  (bh%8 -> XCD affinity)
    int qt = blockIdx.y;                // 0..7
    int b = bh >> 4, h = bh & 15;
    int t = threadIdx.x, w = t >> 6, lane = t & 63;
    int l31 = lane & 31, hl = lane >> 5;
    const float scale2 = 0.1275174333f; // (1/sqrt(128)) * log2(e)

    // Q as B-operand frags (32x32x16): lane holds Q[row=l31][d = c*16 + hl*8 + j]
    bf16x8 qf[12];
    {
        size_t rbase = (size_t)(b * S_LEN + qt * 256 + w * 32 + l31) * QK_LD
                       + h * 192 + hl * 8;
#pragma unroll
        for (int c = 0; c < 12; ++c)
            qf[c] = *(const bf16x8*)(qbuf + rbase + c * 16);
    }

    f32x16 oacc[4] = {};                // [dg]  32q x 128d per wave
    float denom = 0.f;
    const bf16* kb_base = kbuf + (size_t)b * S_LEN * QK_LD + h * 192;
    const bf16* vt_base = vt + (size_t)bh * 128 * S_LEN;

    // ---- staging index setup (512 threads) ----
    // K tile: 32 rows x 192 bf16 = 768 16B-units; t covers 0..511, t<256 also 512..767.
    // 8B swizzle: u8' = u8 ^ (row&15) -> 2 lanes/8B-slot on reads (free, m136).
    int kg0, klA0, klB0, kg1, klA1, klB1, vg0, vlA0, vlB0;
    {
        int c = t;                      // 0..511
        int kr = c / 24, u = c % 24;
        kg0 = kr * QK_LD + u * 8;
        int m = kr & 15;
        klA0 = kr * 192 + (((2 * u) ^ m) << 2);
        klB0 = kr * 192 + (((2 * u + 1) ^ m) << 2);
    }
    {
        int c = t + 512;                // 512..767 (valid for t<256)
        int kr = c / 24, u = c % 24;
        kg1 = kr * QK_LD + u * 8;
        int m = kr & 15;
        klA1 = kr * 192 + (((2 * u) ^ m) << 2);
        klB1 = kr * 192 + (((2 * u + 1) ^ m) << 2);
    }
    {
        // V tile: 128 rows x 32 k = 512 16B-units; rows 64B -> swizzle across
        // row-pairs (128B line): slot16 = (8*(d&1) + k8) ^ ((d>>1)&15)
        int c = t;                      // 0..511
        int vd = c >> 2, u = c & 3;
        vg0 = vd * S_LEN + u * 8;
        int line = vd >> 1, lm = line & 15;
        int sl = 8 * (vd & 1) + 2 * u;
        vlA0 = line * 64 + ((sl ^ lm) << 2);
        vlB0 = line * 64 + (((sl + 1) ^ lm) << 2);
    }
    bool kx = (t < 256);

    // read-side per-lane constants
    int mK = l31 & 15;                  // K swizzle mask (row = l31)
    int kRow = l31 * 192;
    int vLM = l31 >> 1;                 // V line&15 (dg*16 contributes 0 mod 16)
    int vSlotB = 8 * (l31 & 1) + 2 * hl;

    // ---- prologue: stage tile 0 ----
    i32x4 kreg0, kreg1, vreg0;
    kreg0 = *(const i32x4*)(kb_base + kg0);
    if (kx) kreg1 = *(const i32x4*)(kb_base + kg1);
    vreg0 = *(const i32x4*)(vt_base + vg0);
    {
        i32x2 lo; lo[0] = kreg0[0]; lo[1] = kreg0[1];
        i32x2 hi; hi[0] = kreg0[2]; hi[1] = kreg0[3];
        *(i32x2*)&Ks[0][klA0] = lo;
        *(i32x2*)&Ks[0][klB0] = hi;
        if (kx) {
            i32x2 lo1; lo1[0] = kreg1[0]; lo1[1] = kreg1[1];
            i32x2 hi1; hi1[0] = kreg1[2]; hi1[1] = kreg1[3];
            *(i32x2*)&Ks[0][klA1] = lo1;
            *(i32x2*)&Ks[0][klB1] = hi1;
        }
        i32x2 lov; lov[0] = vreg0[0]; lov[1] = vreg0[1];
        i32x2 hiv; hiv[0] = vreg0[2]; hiv[1] = vreg0[3];
        *(i32x2*)&Vs[0][vlA0] = lov;
        *(i32x2*)&Vs[0][vlB0] = hiv;
    }
    __syncthreads();

    int cur = 0;
    for (int kt = 0; kt < 64; ++kt) {
        // prefetch tile kt+1 (lands under compute)
        if (kt < 63) {
            const bf16* kb = kb_base + (size_t)(kt + 1) * 32 * QK_LD;
            kreg0 = *(const i32x4*)(kb + kg0);
            if (kx) kreg1 = *(const i32x4*)(kb + kg1);
            vreg0 = *(const i32x4*)(vt_base + (kt + 1) * 32 + vg0);
        }

        // QK^T: S^T = K(32k x 16d) . Q^T(16d x 32q) per chunk; 12 chunks
        f32x16 sacc = {};
        __builtin_amdgcn_s_setprio(1);
#pragma unroll
        for (int c = 0; c < 12; ++c) {
            int u0 = 4 * c + 2 * hl;
            i32x2 lo = *(const i32x2*)&Ks[cur][kRow + ((u0 ^ mK) << 2)];
            i32x2 hi = *(const i32x2*)&Ks[cur][kRow + (((u0 + 1) ^ mK) << 2)];
            i32x4 kv; kv[0] = lo[0]; kv[1] = lo[1]; kv[2] = hi[0]; kv[3] = hi[1];
            bf16x8 kb = __builtin_bit_cast(bf16x8, kv);
            sacc = __builtin_amdgcn_mfma_f32_32x32x16_bf16(kb, qf[c], sacc, 0, 0, 0);
        }
        __builtin_amdgcn_s_setprio(0);

        // softmax + in-register P redistribution (32x32 layout).
        // lane holds S[k=(r&3)+8*(r>>2)+4*hl][q=l31]; PV A-frag needs
        // P[q=l31][k = s*16 + hl*8 + j]. Exchange lane l <-> l^32.
        unsigned W[8], pw[8];
#pragma unroll
        for (int m = 0; m < 8; ++m) {
            float e0 = __builtin_amdgcn_exp2f(fminf(sacc[2 * m] * scale2, 72.0f));
            float e1 = __builtin_amdgcn_exp2f(fminf(sacc[2 * m + 1] * scale2, 72.0f));
            denom += e0 + e1;
            W[m] = packbf(e0, e1);
        }
#pragma unroll
        for (int m = 0; m < 8; ++m)
            pw[m] = (unsigned)__shfl_xor((int)W[m], 32, 64);
        bf16x8 paf[2];
#pragma unroll
        for (int s = 0; s < 2; ++s) {
            unsigned A = hl ? pw[4 * s + 2] : W[4 * s + 0];
            unsigned B = hl ? pw[4 * s + 3] : W[4 * s + 1];
            unsigned C = hl ? W[4 * s + 2] : pw[4 * s + 0];
            unsigned D = hl ? W[4 * s + 3] : pw[4 * s + 1];
            i32x4 di; di[0] = (int)A; di[1] = (int)B; di[2] = (int)C; di[3] = (int)D;
            paf[s] = __builtin_bit_cast(bf16x8, di);
        }

        // PV: P(32q x 16k) . V(16k x 32d); 4 d-groups x 2 k-steps
        __builtin_amdgcn_s_setprio(1);
#pragma unroll
        for (int dg = 0; dg < 4; ++dg) {
#pragma unroll
            for (int s = 0; s < 2; ++s) {
                int line = dg * 16 + (l31 >> 1);
                int s0 = (vSlotB + 4 * s) ^ vLM;
                int s1 = (vSlotB + 4 * s + 1) ^ vLM;
                i32x2 lo = *(const i32x2*)&Vs[cur][line * 64 + (s0 << 2)];
                i32x2 hi = *(const i32x2*)&Vs[cur][line * 64 + (s1 << 2)];
                i32x4 vv; vv[0] = lo[0]; vv[1] = lo[1]; vv[2] = hi[0]; vv[3] = hi[1];
                bf16x8 vb = __builtin_bit_cast(bf16x8, vv);
                oacc[dg] = __builtin_amdgcn_mfma_f32_32x32x16_bf16(
                    paf[s], vb, oacc[dg], 0, 0, 0);
            }
        }
        __builtin_amdgcn_s_setprio(0);

        // write tile kt+1 into the other buffer; single barrier per tile
        if (kt < 63) {
            i32x2 lo; lo[0] = kreg0[0]; lo[1] = kreg0[1];
            i32x2 hi; hi[0] = kreg0[2]; hi[1] = kreg0[3];
            *(i32x2*)&Ks[cur ^ 1][klA0] = lo;
            *(i32x2*)&Ks[cur ^ 1][klB0] = hi;
            if (kx) {
                i32x2 lo1; lo1[0] = kreg1[0]; lo1[1] = kreg1[1];
                i32x2 hi1; hi1[0] = kreg1[2]; hi1[1] = kreg1[3];
                *(i32x2*)&Ks[cur ^ 1][klA1] = lo1;
                *(i32x2*)&Ks[cur ^ 1][klB1] = hi1;
            }
            i32x2 lov; lov[0] = vreg0[0]; lov[1] = vreg0[1];
            i32x2 hiv; hiv[0] = vreg0[2]; hiv[1] = vreg0[3];
            *(i32x2*)&Vs[cur ^ 1][vlA0] = lov;
            *(i32x2*)&Vs[cur ^ 1][vlB0] = hiv;
        }
        __syncthreads();
        cur ^= 1;
    }

    // denom: lanes l31 and l31+32 hold disjoint k-halves for q=l31
    denom += __shfl_xor(denom, 32, 64);

#pragma unroll
    for (int r = 0; r < 16; ++r) {
        int rowl = (r & 3) + 8 * (r >> 2) + 4 * hl;      // q within the wave's 32
        float dv = __shfl(denom, rowl, 64);              // lane rowl holds q
        float inv = 1.0f / dv;
        int row = qt * 256 + w * 32 + rowl;
#pragma unroll
        for (int dg = 0; dg < 4; ++dg) {
            int col = h * 128 + dg * 32 + l31;
            attnout[(size_t)(b * S_LEN + row) * 2048 + col] =
                (bf16)(oacc[dg][r] * inv);
        }
    }
}

extern "C" void kernel_launch(void* const* d_in, const int* in_sizes, int n_in,
                              void* d_out, int out_size, void* d_ws, size_t ws_size,
                              hipStream_t stream) {
    const float* x   = (const float*)d_in[0];
    const float* Wd  = (const float*)d_in[1];
    const float* bd  = (const float*)d_in[2];
    const float* Wu  = (const float*)d_in[3];
    const float* bu  = (const float*)d_in[4];
    const float* Wqd = (const float*)d_in[5];
    const float* bqd = (const float*)d_in[6];
    const float* Wqu = (const float*)d_in[7];
    const float* bqu = (const float*)d_in[8];
    const float* Wqr = (const float*)d_in[9];
    const float* bqr = (const float*)d_in[10];
    const float* Wkr = (const float*)d_in[11];
    const float* bkr = (const float*)d_in[12];
    const float* Wo  = (const float*)d_in[13];
    const float* bo  = (const float*)d_in[14];
    float* out = (float*)d_out;

    char* p = (char*)d_ws;
    auto alloc = [&](size_t n) { char* r = p; p += (n + 255) & ~(size_t)255; return r; };
    bf16* xb    = (bf16*)alloc((size_t)4096 * 2048 * 2);
    bf16* W1T   = (bf16*)alloc((size_t)2304 * 2048 * 2);   // [Wd|Wqd|Wkr]^T
    bf16* W2T   = (bf16*)alloc((size_t)3072 * 768 * 2);    // [Wqu|Wqr]^T
    bf16* WuT   = (bf16*)alloc((size_t)2048 * 512 * 2);
    bf16* WoT   = (bf16*)alloc((size_t)2048 * 2048 * 2);
    bf16* xproj = (bf16*)alloc((size_t)4096 * 2304 * 2);   // [kvc|qcmp]
    bf16* qbuf  = (bf16*)alloc((size_t)4096 * 3072 * 2);
    bf16* kbuf  = (bf16*)alloc((size_t)4096 * 3072 * 2);
    bf16* vt    = (bf16*)alloc((size_t)32 * 128 * 2048 * 2);
    bf16* aout  = (bf16*)alloc((size_t)4096 * 2048 * 2);
    float* bcat = (float*)alloc((size_t)5376 * 4);
    float2* tab = (float2*)alloc((size_t)65536 * 8);

    cast_f32_bf16<<<dim3(4096), dim3(256), 0, stream>>>(x, xb);

    TArgs ta;
    ta.s[0] = {Wd,  W1T,                       2048, 512,  0};
    ta.s[1] = {Wqd, W1T + (size_t)512 * 2048,  2048, 768,  256};
    ta.s[2] = {Wkr, W1T + (size_t)1280 * 2048, 2048, 1024, 640};
    ta.s[3] = {Wqu, W2T,                       768,  2048, 1152};
    ta.s[4] = {Wqr, W2T + (size_t)2048 * 768,  768,  1024, 1536};
    ta.s[5] = {Wu,  WuT,                       512,  2048, 1728};
    ta.s[6] = {Wo,  WoT,                       2048, 2048, 1984};
    transpose_all<<<dim3(3008), dim3(256), 0, stream>>>(ta);
    setup_small<<<dim3(277), dim3(256), 0, stream>>>(bd, bqd, bkr, bqu, bqr, bcat, tab);

    // GEMM1: x @ [Wd|Wqd|Wkr] -> xproj cols 0..1279, rope(k_r) -> kbuf
    gemm_bt<<<dim3(18, 32), dim3(256), 0, stream>>>(xb, 2048, W1T, bcat,
                                                    xproj, kbuf, 2304, 2048, 4, tab);
    // fused: kvc @ Wu -> kbuf + vt; qcmp @ [Wqu|Wqr] -> qbuf (+rope)
    gemm_up<<<dim3(40, 32), dim3(256), 0, stream>>>(xproj, WuT, bu, kbuf, vt,
                                                    W2T, bcat + 2304, qbuf, tab);

    attn<<<dim3(32, 8), dim3(512), 0, stream>>>(qbuf, kbuf, vt, aout);

    gemm_bt<<<dim3(16, 32), dim3(256), 0, stream>>>(aout, 2048, WoT, bo,
                                                    out, nullptr, 2048, 2048, 1, tab);
}

// Round 12
// 425.091 us; speedup vs baseline: 1.9524x; 1.0102x over previous
//
#include <hip/hip_runtime.h>
#include <cmath>

typedef __bf16 bf16;
typedef __bf16 bf16x8 __attribute__((ext_vector_type(8)));
typedef __bf16 bf16x4 __attribute__((ext_vector_type(4)));
typedef __bf16 bf16x2 __attribute__((ext_vector_type(2)));
typedef float f32x4 __attribute__((ext_vector_type(4)));
typedef float f32x16 __attribute__((ext_vector_type(16)));
typedef int i32x4 __attribute__((ext_vector_type(4)));
typedef int i32x2 __attribute__((ext_vector_type(2)));

#define S_LEN 2048
#define QK_LD 3072       // NHEADS * 192

__device__ __forceinline__ void async_copy16(const bf16* g, bf16* l) {
    __builtin_amdgcn_global_load_lds(
        (const __attribute__((address_space(1))) void*)g,
        (__attribute__((address_space(3))) void*)l, 16, 0, 0);
}

__device__ __forceinline__ unsigned packbf(float a, float b) {
    bf16x2 v; v[0] = (bf16)a; v[1] = (bf16)b;
    return __builtin_bit_cast(unsigned, v);
}

// ---------------- cast x (fp32) -> bf16 ----------------
__global__ __launch_bounds__(256) void cast_f32_bf16(const float* __restrict__ in,
                                                     bf16* __restrict__ out) {
    size_t i = ((size_t)blockIdx.x * 256 + threadIdx.x) * 8;
    float4 a = *(const float4*)(in + i);
    float4 b = *(const float4*)(in + i + 4);
    bf16x8 v;
    v[0] = (bf16)a.x; v[1] = (bf16)a.y; v[2] = (bf16)a.z; v[3] = (bf16)a.w;
    v[4] = (bf16)b.x; v[5] = (bf16)b.y; v[6] = (bf16)b.z; v[7] = (bf16)b.w;
    *(bf16x8*)(out + i) = v;
}

// ---------------- fused transpose-cast of all 7 weights, one dispatch ----------------
struct TSeg { const float* src; bf16* dst; int K, N, blk0; };
struct TArgs { TSeg s[7]; };

__global__ __launch_bounds__(256) void transpose_all(TArgs a) {
    __shared__ float tile[64][68];
    int b = blockIdx.x, si = 0;
#pragma unroll
    for (int i = 1; i < 7; ++i) if (b >= a.s[i].blk0) si = i;
    TSeg sg = a.s[si];
    int local = b - sg.blk0;
    int kTiles = sg.K >> 6;
    int kt = local % kTiles, nt = local / kTiles;
    int k0 = kt * 64, n0 = nt * 64;
    int K = sg.K, N = sg.N;
    int t = threadIdx.x;
#pragma unroll
    for (int i = 0; i < 4; ++i) {
        int c = t + i * 256;
        int r = c >> 4, off = (c & 15) * 4;
        float4 v = *(const float4*)(sg.src + (size_t)(k0 + r) * N + n0 + off);
        tile[r][off] = v.x; tile[r][off + 1] = v.y;
        tile[r][off + 2] = v.z; tile[r][off + 3] = v.w;
    }
    __syncthreads();
#pragma unroll
    for (int i = 0; i < 2; ++i) {
        int c = t + i * 256;
        int nr = c >> 3, koff = (c & 7) * 8;
        bf16x8 v;
#pragma unroll
        for (int j = 0; j < 8; ++j) v[j] = (bf16)tile[koff + j][nr];
        *(bf16x8*)(sg.dst + (size_t)(n0 + nr) * K + k0 + koff) = v;
    }
}

// ---------------- bias concat + rope table, one dispatch ----------------
__global__ __launch_bounds__(256) void setup_small(const float* __restrict__ bd,
                                                   const float* __restrict__ bqd,
                                                   const float* __restrict__ bkr,
                                                   const float* __restrict__ bqu,
                                                   const float* __restrict__ bqr,
                                                   float* __restrict__ bcat,
                                                   float2* __restrict__ tab) {
    if (blockIdx.x < 21) {
        int i = blockIdx.x * 256 + threadIdx.x;
        if (i < 512) bcat[i] = bd[i];
        else if (i < 1280) bcat[i] = bqd[i - 512];
        else if (i < 2304) bcat[i] = bkr[i - 1280];
        else if (i < 4352) bcat[i] = bqu[i - 2304];
        else if (i < 5376) bcat[i] = bqr[i - 4352];
    } else {
        int id = (blockIdx.x - 21) * 256 + threadIdx.x;   // 65536
        int s = id >> 5, i = id & 31;
        float f = expf(-0.2878231366242557f * (float)i);  // ln(10000)/32
        float ang = (float)s * f;
        tab[id] = make_float2(cosf(ang), sinf(ang));
    }
}

// ---------------- m97-style bf16 GEMM core with fused epilogues ----------------
// mode 1: fp32 out0, stride Ndim
// mode 4: col<1280 -> bf16 out0 (xproj, stride 2304); col>=1280 -> rope -> out1 (kbuf)
// mode 5: col<2048 -> head-scatter out0 (qbuf); col>=2048 -> rope -> out0 (qbuf)
// mode 6: head-scatter out0 (kbuf) + transposed pack out1 (vt[bh][d][s])
__device__ __forceinline__ void gemm_core(const bf16* __restrict__ A, int lda,
                                          const bf16* __restrict__ Bt,
                                          const float* __restrict__ bias,
                                          void* __restrict__ out0,
                                          void* __restrict__ out1,
                                          int Ndim, int Kdim, int mode,
                                          const float2* __restrict__ tab,
                                          int bn, int bm, bf16* As, bf16* Bs) {
    int t = threadIdx.x;
    int w = t >> 6, lane = t & 63;
    int wm = (w >> 1) * 64, wn = (w & 1) * 64;
    int l15 = lane & 15, q4 = lane >> 4;
    f32x4 acc[4][4] = {};

    int lrow = lane >> 2;
    int lcol = (lane & 3) * 8;
    int c0 = w * 2, c1 = w * 2 + 1;
    const bf16* aS0 = A  + (size_t)(bm * 128 + c0 * 16 + lrow) * lda + lcol;
    const bf16* aS1 = A  + (size_t)(bm * 128 + c1 * 16 + lrow) * lda + lcol;
    const bf16* bS0 = Bt + (size_t)(bn * 128 + c0 * 16 + lrow) * Kdim + lcol;
    const bf16* bS1 = Bt + (size_t)(bn * 128 + c1 * 16 + lrow) * Kdim + lcol;
    bf16* aD0 = &As[c0 * 512]; bf16* aD1 = &As[c1 * 512];
    bf16* bD0 = &Bs[c0 * 512]; bf16* bD1 = &Bs[c1 * 512];

    for (int kt = 0; kt < Kdim; kt += 32) {
        async_copy16(aS0 + kt, aD0);
        async_copy16(aS1 + kt, aD1);
        async_copy16(bS0 + kt, bD0);
        async_copy16(bS1 + kt, bD1);
        __syncthreads();
        bf16x8 af[4], bfr[4];
#pragma unroll
        for (int mb = 0; mb < 4; ++mb)
            af[mb] = *(const bf16x8*)&As[(wm + mb * 16 + l15) * 32 + q4 * 8];
#pragma unroll
        for (int nb = 0; nb < 4; ++nb)
            bfr[nb] = *(const bf16x8*)&Bs[(wn + nb * 16 + l15) * 32 + q4 * 8];
#pragma unroll
        for (int mb = 0; mb < 4; ++mb)
#pragma unroll
            for (int nb = 0; nb < 4; ++nb)
                acc[mb][nb] = __builtin_amdgcn_mfma_f32_16x16x32_bf16(
                    af[mb], bfr[nb], acc[mb][nb], 0, 0, 0);
        __syncthreads();
    }

#pragma unroll
    for (int mb = 0; mb < 4; ++mb) {
        int row = bm * 128 + wm + mb * 16 + q4 * 4;
#pragma unroll
        for (int nb = 0; nb < 4; ++nb) {
            int col = bn * 128 + wn + nb * 16 + l15;
            float bv = bias[col];
            if (mode == 1) {
#pragma unroll
                for (int r = 0; r < 4; ++r)
                    ((float*)out0)[(size_t)(row + r) * Ndim + col] = acc[mb][nb][r] + bv;
            } else if (mode == 4) {
                if (col < 1280) {
#pragma unroll
                    for (int r = 0; r < 4; ++r)
                        ((bf16*)out0)[(size_t)(row + r) * 2304 + col] =
                            (bf16)(acc[mb][nb][r] + bv);
                } else {
                    int rel = col - 1280;
                    int hh = rel >> 6, idx = rel & 63, ii = idx >> 1, odd = idx & 1;
#pragma unroll
                    for (int r = 0; r < 4; ++r) {
                        float vv = acc[mb][nb][r] + bv;
                        float pp = __shfl_xor(vv, 1, 64);
                        float2 cs = tab[((row + r) & 2047) * 32 + ii];
                        float o = vv * cs.x + (odd ? pp * cs.y : -pp * cs.y);
                        ((bf16*)out1)[(size_t)(row + r) * QK_LD + hh * 192 + 128 + idx] =
                            (bf16)o;
                    }
                }
            } else if (mode == 5) {
                if (col < 2048) {
                    int hh = col >> 7, dd = col & 127;
#pragma unroll
                    for (int r = 0; r < 4; ++r)
                        ((bf16*)out0)[(size_t)(row + r) * QK_LD + hh * 192 + dd] =
                            (bf16)(acc[mb][nb][r] + bv);
                } else {
                    int rel = col - 2048;
                    int hh = rel >> 6, idx = rel & 63, ii = idx >> 1, odd = idx & 1;
#pragma unroll
                    for (int r = 0; r < 4; ++r) {
                        float vv = acc[mb][nb][r] + bv;
                        float pp = __shfl_xor(vv, 1, 64);
                        float2 cs = tab[((row + r) & 2047) * 32 + ii];
                        float o = vv * cs.x + (odd ? pp * cs.y : -pp * cs.y);
                        ((bf16*)out0)[(size_t)(row + r) * QK_LD + hh * 192 + 128 + idx] =
                            (bf16)o;
                    }
                }
            } else {   // mode 6: kv_up -> kbuf scatter + vt transpose-pack
                int hh = col >> 7, dd = col & 127;
                bf16x4 pack;
#pragma unroll
                for (int r = 0; r < 4; ++r) {
                    float vv = acc[mb][nb][r] + bv;
                    ((bf16*)out0)[(size_t)(row + r) * QK_LD + hh * 192 + dd] = (bf16)vv;
                    pack[r] = (bf16)vv;
                }
                int bidx = row >> 11, srow = row & 2047;
                *(bf16x4*)((bf16*)out1 +
                           ((size_t)(bidx * 16 + hh) * 128 + dd) * S_LEN + srow) = pack;
            }
        }
    }
}

__global__ __launch_bounds__(256) void gemm_bt(const bf16* __restrict__ A, int lda,
                                               const bf16* __restrict__ Bt,
                                               const float* __restrict__ bias,
                                               void* __restrict__ out0,
                                               void* __restrict__ out1,
                                               int Ndim, int Kdim, int mode,
                                               const float2* __restrict__ tab) {
    __shared__ bf16 As[128 * 32];
    __shared__ bf16 Bs[128 * 32];
    gemm_core(A, lda, Bt, bias, out0, out1, Ndim, Kdim, mode, tab,
              blockIdx.x, blockIdx.y, As, Bs);
}

// fused up-projection GEMMs: bn<16 -> kv_up (mode 6, K=512); bn>=16 -> q_up (mode 5, K=768)
__global__ __launch_bounds__(256) void gemm_up(const bf16* __restrict__ xproj,
                                               const bf16* __restrict__ WuT,
                                               const float* __restrict__ bu,
                                               void* __restrict__ kbuf,
                                               void* __restrict__ vt,
                                               const bf16* __restrict__ W2T,
                                               const float* __restrict__ bq,
                                               void* __restrict__ qbuf,
                                               const float2* __restrict__ tab) {
    __shared__ bf16 As[128 * 32];
    __shared__ bf16 Bs[128 * 32];
    int bn = blockIdx.x;
    if (bn < 16)
        gemm_core(xproj, 2304, WuT, bu, kbuf, vt, 2048, 512, 6, tab,
                  bn, blockIdx.y, As, Bs);
    else
        gemm_core(xproj + 512, 2304, W2T, bq, qbuf, nullptr, 3072, 768, 5, tab,
                  bn - 16, blockIdx.y, As, Bs);
}

// ---------------- attention v14: v8-final + permlane32_swap P-redistribution ----------------
// T12 primitive: v_permlane32_swap_b32 does the lane l <-> l^32 exchange on the
// VALU pipe (1.20x vs ds_bpermute, m255) and each swap yields BOTH output words:
// swap(W[4s],W[4s+2]) -> (word A, word C); swap(W[4s+1],W[4s+3]) -> (B, D).
// Replaces 8 bpermutes (LDS pipe, contended) + 8 selects with 4 swaps per tile.
__global__ __launch_bounds__(512, 2) void attn(const bf16* __restrict__ qbuf,
                                               const bf16* __restrict__ kbuf,
                                               const bf16* __restrict__ vt,
                                               bf16* __restrict__ attnout) {
    __shared__ bf16 Ks[2][32 * 192];    // 32 keys x 192d; 8B-unit swz: u8 ^ (row&15)
    __shared__ bf16 Vs[2][128 * 32];    // 128 d x 32 k; line-pair swz
    int bh = blockIdx.x;                // 0..31  (bh%8 -> XCD affinity)
    int qt = blockIdx.y;                // 0..7
    int b = bh >> 4, h = bh & 15;
    int t = threadIdx.x, w = t >> 6, lane = t & 63;
    int l31 = lane & 31, hl = lane >> 5;
    const float scale2 = 0.1275174333f; // (1/sqrt(128)) * log2(e)

    // Q as B-operand frags (32x32x16): lane holds Q[row=l31][d = c*16 + hl*8 + j]
    bf16x8 qf[12];
    {
        size_t rbase = (size_t)(b * S_LEN + qt * 256 + w * 32 + l31) * QK_LD
                       + h * 192 + hl * 8;
#pragma unroll
        for (int c = 0; c < 12; ++c)
            qf[c] = *(const bf16x8*)(qbuf + rbase + c * 16);
    }

    f32x16 oacc[4] = {};                // [dg]  32q x 128d per wave
    float denom = 0.f;
    const bf16* kb_base = kbuf + (size_t)b * S_LEN * QK_LD + h * 192;
    const bf16* vt_base = vt + (size_t)bh * 128 * S_LEN;

    // ---- staging index setup (512 threads) ----
    int kg0, klA0, klB0, kg1, klA1, klB1, vg0, vlA0, vlB0;
    {
        int c = t;                      // 0..511
        int kr = c / 24, u = c % 24;
        kg0 = kr * QK_LD + u * 8;
        int m = kr & 15;
        klA0 = kr * 192 + (((2 * u) ^ m) << 2);
        klB0 = kr * 192 + (((2 * u + 1) ^ m) << 2);
    }
    {
        int c = t + 512;                // 512..767 (valid for t<256)
        int kr = c / 24, u = c % 24;
        kg1 = kr * QK_LD + u * 8;
        int m = kr & 15;
        klA1 = kr * 192 + (((2 * u) ^ m) << 2);
        klB1 = kr * 192 + (((2 * u + 1) ^ m) << 2);
    }
    {
        int c = t;                      // 0..511
        int vd = c >> 2, u = c & 3;
        vg0 = vd * S_LEN + u * 8;
        int line = vd >> 1, lm = line & 15;
        int sl = 8 * (vd & 1) + 2 * u;
        vlA0 = line * 64 + ((sl ^ lm) << 2);
        vlB0 = line * 64 + (((sl + 1) ^ lm) << 2);
    }
    bool kx = (t < 256);

    // read-side per-lane constants
    int mK = l31 & 15;                  // K swizzle mask (row = l31)
    int kRow = l31 * 192;
    int vLM = l31 >> 1;                 // V line&15 (dg*16 contributes 0 mod 16)
    int vSlotB = 8 * (l31 & 1) + 2 * hl;

    // ---- prologue: stage tile 0 ----
    i32x4 kreg0, kreg1, vreg0;
    kreg0 = *(const i32x4*)(kb_base + kg0);
    if (kx) kreg1 = *(const i32x4*)(kb_base + kg1);
    vreg0 = *(const i32x4*)(vt_base + vg0);
    {
        i32x2 lo; lo[0] = kreg0[0]; lo[1] = kreg0[1];
        i32x2 hi; hi[0] = kreg0[2]; hi[1] = kreg0[3];
        *(i32x2*)&Ks[0][klA0] = lo;
        *(i32x2*)&Ks[0][klB0] = hi;
        if (kx) {
            i32x2 lo1; lo1[0] = kreg1[0]; lo1[1] = kreg1[1];
            i32x2 hi1; hi1[0] = kreg1[2]; hi1[1] = kreg1[3];
            *(i32x2*)&Ks[0][klA1] = lo1;
            *(i32x2*)&Ks[0][klB1] = hi1;
        }
        i32x2 lov; lov[0] = vreg0[0]; lov[1] = vreg0[1];
        i32x2 hiv; hiv[0] = vreg0[2]; hiv[1] = vreg0[3];
        *(i32x2*)&Vs[0][vlA0] = lov;
        *(i32x2*)&Vs[0][vlB0] = hiv;
    }
    __syncthreads();

    int cur = 0;
    for (int kt = 0; kt < 64; ++kt) {
        // prefetch tile kt+1 (lands under compute)
        if (kt < 63) {
            const bf16* kb = kb_base + (size_t)(kt + 1) * 32 * QK_LD;
            kreg0 = *(const i32x4*)(kb + kg0);
            if (kx) kreg1 = *(const i32x4*)(kb + kg1);
            vreg0 = *(const i32x4*)(vt_base + (kt + 1) * 32 + vg0);
        }

        // QK^T: S^T = K(32k x 16d) . Q^T(16d x 32q) per chunk; 12 chunks
        f32x16 sacc = {};
        __builtin_amdgcn_s_setprio(1);
#pragma unroll
        for (int c = 0; c < 12; ++c) {
            int u0 = 4 * c + 2 * hl;
            i32x2 lo = *(const i32x2*)&Ks[cur][kRow + ((u0 ^ mK) << 2)];
            i32x2 hi = *(const i32x2*)&Ks[cur][kRow + (((u0 + 1) ^ mK) << 2)];
            i32x4 kv; kv[0] = lo[0]; kv[1] = lo[1]; kv[2] = hi[0]; kv[3] = hi[1];
            bf16x8 kb = __builtin_bit_cast(bf16x8, kv);
            sacc = __builtin_amdgcn_mfma_f32_32x32x16_bf16(kb, qf[c], sacc, 0, 0, 0);
        }
        __builtin_amdgcn_s_setprio(0);

        // softmax + in-register P redistribution via permlane32_swap.
        // lane holds S[k=(r&3)+8*(r>>2)+4*hl][q=l31]; PV A-frag needs
        // P[q=l31][k = s*16 + hl*8 + j] -- exchange lane l <-> l^32.
        unsigned W[8];
#pragma unroll
        for (int m = 0; m < 8; ++m) {
            float e0 = __builtin_amdgcn_exp2f(fminf(sacc[2 * m] * scale2, 72.0f));
            float e1 = __builtin_amdgcn_exp2f(fminf(sacc[2 * m + 1] * scale2, 72.0f));
            denom += e0 + e1;
            W[m] = packbf(e0, e1);
        }
        bf16x8 paf[2];
#pragma unroll
        for (int s = 0; s < 2; ++s) {
            i32x2 rA = __builtin_amdgcn_permlane32_swap(
                (int)W[4 * s + 0], (int)W[4 * s + 2], false, false);
            i32x2 rB = __builtin_amdgcn_permlane32_swap(
                (int)W[4 * s + 1], (int)W[4 * s + 3], false, false);
            i32x4 di; di[0] = rA[0]; di[1] = rB[0]; di[2] = rA[1]; di[3] = rB[1];
            paf[s] = __builtin_bit_cast(bf16x8, di);
        }

        // PV: P(32q x 16k) . V(16k x 32d); 4 d-groups x 2 k-steps
        __builtin_amdgcn_s_setprio(1);
#pragma unroll
        for (int dg = 0; dg < 4; ++dg) {
#pragma unroll
            for (int s = 0; s < 2; ++s) {
                int line = dg * 16 + (l31 >> 1);
                int s0 = (vSlotB + 4 * s) ^ vLM;
                int s1 = (vSlotB + 4 * s + 1) ^ vLM;
                i32x2 lo = *(const i32x2*)&Vs[cur][line * 64 + (s0 << 2)];
                i32x2 hi = *(const i32x2*)&Vs[cur][line * 64 + (s1 << 2)];
                i32x4 vv; vv[0] = lo[0]; vv[1] = lo[1]; vv[2] = hi[0]; vv[3] = hi[1];
                bf16x8 vb = __builtin_bit_cast(bf16x8, vv);
                oacc[dg] = __builtin_amdgcn_mfma_f32_32x32x16_bf16(
                    paf[s], vb, oacc[dg], 0, 0, 0);
            }
        }
        __builtin_amdgcn_s_setprio(0);

        // write tile kt+1 into the other buffer; single barrier per tile
        if (kt < 63) {
            i32x2 lo; lo[0] = kreg0[0]; lo[1] = kreg0[1];
            i32x2 hi; hi[0] = kreg0[2]; hi[1] = kreg0[3];
            *(i32x2*)&Ks[cur ^ 1][klA0] = lo;
            *(i32x2*)&Ks[cur ^ 1][klB0] = hi;
            if (kx) {
                i32x2 lo1; lo1[0] = kreg1[0]; lo1[1] = kreg1[1];
                i32x2 hi1; hi1[0] = kreg1[2]; hi1[1] = kreg1[3];
                *(i32x2*)&Ks[cur ^ 1][klA1] = lo1;
                *(i32x2*)&Ks[cur ^ 1][klB1] = hi1;
            }
            i32x2 lov; lov[0] = vreg0[0]; lov[1] = vreg0[1];
            i32x2 hiv; hiv[0] = vreg0[2]; hiv[1] = vreg0[3];
            *(i32x2*)&Vs[cur ^ 1][vlA0] = lov;
            *(i32x2*)&Vs[cur ^ 1][vlB0] = hiv;
        }
        __syncthreads();
        cur ^= 1;
    }

    // denom: lanes l31 and l31+32 hold disjoint k-halves for q=l31
    denom += __shfl_xor(denom, 32, 64);

#pragma unroll
    for (int r = 0; r < 16; ++r) {
        int rowl = (r & 3) + 8 * (r >> 2) + 4 * hl;      // q within the wave's 32
        float dv = __shfl(denom, rowl, 64);              // lane rowl holds q
        float inv = 1.0f / dv;
        int row = qt * 256 + w * 32 + rowl;
#pragma unroll
        for (int dg = 0; dg < 4; ++dg) {
            int col = h * 128 + dg * 32 + l31;
            attnout[(size_t)(b * S_LEN + row) * 2048 + col] =
                (bf16)(oacc[dg][r] * inv);
        }
    }
}

extern "C" void kernel_launch(void* const* d_in, const int* in_sizes, int n_in,
                              void* d_out, int out_size, void* d_ws, size_t ws_size,
                              hipStream_t stream) {
    const float* x   = (const float*)d_in[0];
    const float* Wd  = (const float*)d_in[1];
    const float* bd  = (const float*)d_in[2];
    const float* Wu  = (const float*)d_in[3];
    const float* bu  = (const float*)d_in[4];
    const float* Wqd = (const float*)d_in[5];
    const float* bqd = (const float*)d_in[6];
    const float* Wqu = (const float*)d_in[7];
    const float* bqu = (const float*)d_in[8];
    const float* Wqr = (const float*)d_in[9];
    const float* bqr = (const float*)d_in[10];
    const float* Wkr = (const float*)d_in[11];
    const float* bkr = (const float*)d_in[12];
    const float* Wo  = (const float*)d_in[13];
    const float* bo  = (const float*)d_in[14];
    float* out = (float*)d_out;

    char* p = (char*)d_ws;
    auto alloc = [&](size_t n) { char* r = p; p += (n + 255) & ~(size_t)255; return r; };
    bf16* xb    = (bf16*)alloc((size_t)4096 * 2048 * 2);
    bf16* W1T   = (bf16*)alloc((size_t)2304 * 2048 * 2);   // [Wd|Wqd|Wkr]^T
    bf16* W2T   = (bf16*)alloc((size_t)3072 * 768 * 2);    // [Wqu|Wqr]^T
    bf16* WuT   = (bf16*)alloc((size_t)2048 * 512 * 2);
    bf16* WoT   = (bf16*)alloc((size_t)2048 * 2048 * 2);
    bf16* xproj = (bf16*)alloc((size_t)4096 * 2304 * 2);   // [kvc|qcmp]
    bf16* qbuf  = (bf16*)alloc((size_t)4096 * 3072 * 2);
    bf16* kbuf  = (bf16*)alloc((size_t)4096 * 3072 * 2);
    bf16* vt    = (bf16*)alloc((size_t)32 * 128 * 2048 * 2);
    bf16* aout  = (bf16*)alloc((size_t)4096 * 2048 * 2);
    float* bcat = (float*)alloc((size_t)5376 * 4);
    float2* tab = (float2*)alloc((size_t)65536 * 8);

    cast_f32_bf16<<<dim3(4096), dim3(256), 0, stream>>>(x, xb);

    TArgs ta;
    ta.s[0] = {Wd,  W1T,                       2048, 512,  0};
    ta.s[1] = {Wqd, W1T + (size_t)512 * 2048,  2048, 768,  256};
    ta.s[2] = {Wkr, W1T + (size_t)1280 * 2048, 2048, 1024, 640};
    ta.s[3] = {Wqu, W2T,                       768,  2048, 1152};
    ta.s[4] = {Wqr, W2T + (size_t)2048 * 768,  768,  1024, 1536};
    ta.s[5] = {Wu,  WuT,                       512,  2048, 1728};
    ta.s[6] = {Wo,  WoT,                       2048, 2048, 1984};
    transpose_all<<<dim3(3008), dim3(256), 0, stream>>>(ta);
    setup_small<<<dim3(277), dim3(256), 0, stream>>>(bd, bqd, bkr, bqu, bqr, bcat, tab);

    // GEMM1: x @ [Wd|Wqd|Wkr] -> xproj cols 0..1279, rope(k_r) -> kbuf
    gemm_bt<<<dim3(18, 32), dim3(256), 0, stream>>>(xb, 2048, W1T, bcat,
                                                    xproj, kbuf, 2304, 2048, 4, tab);
    // fused: kvc @ Wu -> kbuf + vt; qcmp @ [Wqu|Wqr] -> qbuf (+rope)
    gemm_up<<<dim3(40, 32), dim3(256), 0, stream>>>(xproj, WuT, bu, kbuf, vt,
                                                    W2T, bcat + 2304, qbuf, tab);

    attn<<<dim3(32, 8), dim3(512), 0, stream>>>(qbuf, kbuf, vt, aout);

    gemm_bt<<<dim3(16, 32), dim3(256), 0, stream>>>(aout, 2048, WoT, bo,
                                                    out, nullptr, 2048, 2048, 1, tab);
}